// Round 7
// baseline (316.173 us; speedup 1.0000x reference)
//
#include <hip/hip_runtime.h>
#include <hip/hip_bf16.h>

#define NN 100000
#define NE 1600000
#define NG 256
#define FIN 100
#define HH 64

#define BSHIFT 9
#define BSIZE 512
#define NBUCK ((NN + BSIZE - 1) / BSIZE)   // 196
#define CHUNK 4096
#define NPLACE ((NE + CHUNK - 1) / CHUNK)  // 391

#define NBLK64 ((NN + 63) / 64)            // 1563
#define NGRP (NBLK64 * 8)                  // 12504 8-row groups
#define MAXSEG 4

#define SXE 136
#define SH 72

typedef __attribute__((ext_vector_type(8))) short short8;
typedef __attribute__((ext_vector_type(4))) float f32x4;

__device__ __forceinline__ float relu_f(float x){ return x > 0.f ? x : 0.f; }
__device__ __forceinline__ unsigned short f2b(float f) {
    unsigned int u = __float_as_uint(f);
    u += 0x7fffu + ((u >> 16) & 1u);
    return (unsigned short)(u >> 16);
}
__device__ __forceinline__ float b2f(unsigned short h) {
    return __uint_as_float(((unsigned int)h) << 16);
}

// ========= weight prep: transpose + bf16 convert (once) =========
__global__ __launch_bounds__(256) void k_prep(const float* __restrict__ Wemb,
                                              const float* __restrict__ convW,
                                              unsigned short* __restrict__ WeT,   // [64][128]
                                              unsigned short* __restrict__ WcT) { // [3][64][64]
    int t = threadIdx.x;
    for (int i = t; i < 64 * 128; i += 256) WeT[i] = 0;
    __syncthreads();
    for (int i = t; i < FIN * HH; i += 256) {
        int k = i >> 6, n = i & 63;
        WeT[n * 128 + k] = f2b(Wemb[i]);
    }
    for (int l = 0; l < 3; ++l)
        for (int i = t; i < HH * HH; i += 256) {
            int k = i >> 6, n = i & 63;
            WcT[l * 4096 + n * 64 + k] = f2b(convW[l * 4096 + i]);
        }
}

// ================= CSR build =================
__global__ __launch_bounds__(256) void k_bcount(const int* __restrict__ dst,
                                                int* __restrict__ bucket_cnt) {
    __shared__ int h[NBUCK];
    int t = threadIdx.x;
    for (int i = t; i < NBUCK; i += 256) h[i] = 0;
    __syncthreads();
    int e0 = blockIdx.x * CHUNK;
    int e1 = e0 + CHUNK; if (e1 > NE) e1 = NE;
    for (int i = e0 + t; i < e1; i += 256) atomicAdd(&h[dst[i] >> BSHIFT], 1);
    __syncthreads();
    for (int i = t; i < NBUCK; i += 256) { int c = h[i]; if (c) atomicAdd(&bucket_cnt[i], c); }
}

__global__ __launch_bounds__(256) void k_bscan(const int* __restrict__ bucket_cnt,
                                               int* __restrict__ bucket_start,
                                               int* __restrict__ bucket_cur,
                                               int* __restrict__ row_start) {
    int t = threadIdx.x;
    int lane = t & 63, wave = t >> 6;
    __shared__ int wsum[4];
    int v = (t < NBUCK) ? bucket_cnt[t] : 0;
    int inc = v;
    for (int off = 1; off < 64; off <<= 1) {
        int n = __shfl_up(inc, off, 64);
        if (lane >= off) inc += n;
    }
    if (lane == 63) wsum[wave] = inc;
    __syncthreads();
    int woff = 0;
    for (int w = 0; w < wave; ++w) woff += wsum[w];
    int excl = woff + inc - v;
    if (t < NBUCK) { bucket_start[t] = excl; bucket_cur[t] = excl; }
    if (t == 0) { bucket_start[NBUCK] = NE; row_start[NN] = NE; }
}

// pack: (local_dst 9b << 17) | src 17b
__global__ __launch_bounds__(256) void k_bplace(const int* __restrict__ src,
                                                const int* __restrict__ dst,
                                                int* __restrict__ bucket_cur,
                                                unsigned int* __restrict__ upairs) {
    __shared__ int h[NBUCK];
    __shared__ int base[NBUCK];
    int t = threadIdx.x;
    for (int i = t; i < NBUCK; i += 256) h[i] = 0;
    __syncthreads();
    int e0 = blockIdx.x * CHUNK;
    int e1 = e0 + CHUNK; if (e1 > NE) e1 = NE;
    for (int i = e0 + t; i < e1; i += 256) atomicAdd(&h[dst[i] >> BSHIFT], 1);
    __syncthreads();
    for (int i = t; i < NBUCK; i += 256) {
        int c = h[i];
        base[i] = c ? atomicAdd(&bucket_cur[i], c) : 0;
    }
    __syncthreads();
    for (int i = t; i < NBUCK; i += 256) h[i] = 0;
    __syncthreads();
    for (int i = e0 + t; i < e1; i += 256) {
        int d = dst[i];
        int b = d >> BSHIFT;
        int pos = base[b] + atomicAdd(&h[b], 1);
        upairs[pos] = ((unsigned)(d & (BSIZE - 1)) << 17) | (unsigned)src[i];
    }
}

// ===== merged: blocks < NBUCK finalize CSR; rest do embed + GEMM0 (unscaled) =====
__global__ __launch_bounds__(256) void k_csr_embed(const int* __restrict__ bucket_start,
                                                   const unsigned int* __restrict__ upairs,
                                                   int* __restrict__ row_start,
                                                   float* __restrict__ dinv,
                                                   int* __restrict__ csr_src,
                                                   const float* __restrict__ x,
                                                   const unsigned short* __restrict__ WeT,
                                                   const float* __restrict__ bemb,
                                                   const unsigned short* __restrict__ W0T,
                                                   unsigned short* __restrict__ gout) {
    __shared__ int degl[BSIZE];
    __shared__ int curl[BSIZE];
    __shared__ int wsum8[8];
    __shared__ __align__(16) unsigned short Xl[64 * SXE];
    int t = threadIdx.x;
    int lane = t & 63, w = t >> 6;

    if (blockIdx.x < NBUCK) {
        // ---------- CSR finalize ----------
        int b = blockIdx.x;
        int nbase = b << BSHIFT;
        int ncnt = NN - nbase; if (ncnt > BSIZE) ncnt = BSIZE;
        for (int i = t; i < BSIZE; i += 256) degl[i] = 0;
        __syncthreads();
        int p0 = bucket_start[b], p1 = bucket_start[b + 1];
        for (int i = p0 + t; i < p1; i += 256) atomicAdd(&degl[upairs[i] >> 17], 1);
        __syncthreads();
        int vals[2], incs[2];
        #pragma unroll
        for (int k = 0; k < 2; ++k) {
            int seg = w + k * 4;
            int v = degl[seg * 64 + lane];
            int inc = v;
            for (int off = 1; off < 64; off <<= 1) {
                int n = __shfl_up(inc, off, 64);
                if (lane >= off) inc += n;
            }
            vals[k] = v; incs[k] = inc;
            if (lane == 63) wsum8[seg] = inc;
        }
        __syncthreads();
        #pragma unroll
        for (int k = 0; k < 2; ++k) {
            int seg = w + k * 4;
            int soff = 0;
            for (int s = 0; s < 8; ++s) if (s < seg) soff += wsum8[s];
            int idx = seg * 64 + lane;
            int rs = p0 + soff + incs[k] - vals[k];
            curl[idx] = rs;
            if (idx < ncnt) {
                row_start[nbase + idx] = rs;
                dinv[nbase + idx] = rsqrtf((float)(vals[k] + 1));
            }
        }
        __syncthreads();
        for (int i = p0 + t; i < p1; i += 256) {
            unsigned pk = upairs[i];
            int pos = atomicAdd(&curl[pk >> 17], 1);
            csr_src[pos] = (int)(pk & 0x1FFFFu);
        }
        return;
    }

    // ---------- embed + GEMM0 (unscaled output) ----------
    int row0 = (blockIdx.x - NBUCK) * 64;
    for (int i = t; i < 64 * SXE; i += 256) Xl[i] = 0;
    __syncthreads();
    for (int i = t; i < 64 * FIN; i += 256) {
        int r = i / FIN, c = i - r * FIN;
        int row = row0 + r;
        if (row < NN) Xl[r * SXE + c] = f2b(x[(size_t)row * FIN + c]);
    }
    __syncthreads();

    int m16 = lane & 15, g4 = lane >> 4;
    f32x4 acc[4] = {{0,0,0,0},{0,0,0,0},{0,0,0,0},{0,0,0,0}};
    const unsigned short* Arow = &Xl[(w * 16 + m16) * SXE + g4 * 8];
    #pragma unroll
    for (int kk = 0; kk < 4; ++kk) {
        short8 a = *reinterpret_cast<const short8*>(Arow + kk * 32);
        #pragma unroll
        for (int c = 0; c < 4; ++c) {
            short8 bf = *reinterpret_cast<const short8*>(&WeT[(size_t)(c * 16 + m16) * 128 + g4 * 8 + kk * 32]);
            acc[c] = __builtin_amdgcn_mfma_f32_16x16x32_bf16(a, bf, acc[c], 0, 0, 0);
        }
    }
    __syncthreads();
    unsigned short* hl = Xl;        // h-tile aliased, stride SH
    #pragma unroll
    for (int c = 0; c < 4; ++c) {
        int col = c * 16 + m16;
        float bb = bemb[col];
        #pragma unroll
        for (int r = 0; r < 4; ++r) {
            int rr = w * 16 + g4 * 4 + r;
            hl[rr * SH + col] = f2b(relu_f(acc[c][r] + bb));
        }
    }
    __syncthreads();
    f32x4 acc2[4] = {{0,0,0,0},{0,0,0,0},{0,0,0,0},{0,0,0,0}};
    const unsigned short* Hrow = &hl[(w * 16 + m16) * SH + g4 * 8];
    #pragma unroll
    for (int kk = 0; kk < 2; ++kk) {
        short8 a = *reinterpret_cast<const short8*>(Hrow + kk * 32);
        #pragma unroll
        for (int c = 0; c < 4; ++c) {
            short8 bf = *reinterpret_cast<const short8*>(&W0T[(size_t)(c * 16 + m16) * 64 + g4 * 8 + kk * 32]);
            acc2[c] = __builtin_amdgcn_mfma_f32_16x16x32_bf16(a, bf, acc2[c], 0, 0, 0);
        }
    }
    #pragma unroll
    for (int r = 0; r < 4; ++r) {
        int row = row0 + w * 16 + g4 * 4 + r;
        if (row < NN) {
            #pragma unroll
            for (int c = 0; c < 4; ++c) {
                int col = c * 16 + m16;
                gout[(size_t)row * HH + col] = f2b(acc2[c][r]);   // UNSCALED
            }
        }
    }
}

// ======== gather: sum over in-edges; ES=1 applies per-edge dinv[src] ========
template <int ES>
__device__ __forceinline__ float gather_sum(const int* __restrict__ csr_src,
                                            const unsigned short* __restrict__ g,
                                            const float* __restrict__ dinv,
                                            int start, int n, int lane) {
    float acc = 0.f;
    for (int base = 0; base < n; base += 64) {
        int m = n - base; if (m > 64) m = 64;
        int sv = (lane < m) ? csr_src[start + base + lane] : 0;
        float dl = 0.f;
        if (ES) dl = (lane < m) ? dinv[sv] : 0.f;
        int j = 0;
        for (; j + 8 <= m; j += 8) {
            int s0 = __shfl(sv, j),     s1 = __shfl(sv, j + 1);
            int s2 = __shfl(sv, j + 2), s3 = __shfl(sv, j + 3);
            int s4 = __shfl(sv, j + 4), s5 = __shfl(sv, j + 5);
            int s6 = __shfl(sv, j + 6), s7 = __shfl(sv, j + 7);
            float a0 = b2f(g[(size_t)s0 * HH + lane]);
            float a1 = b2f(g[(size_t)s1 * HH + lane]);
            float a2 = b2f(g[(size_t)s2 * HH + lane]);
            float a3 = b2f(g[(size_t)s3 * HH + lane]);
            float a4 = b2f(g[(size_t)s4 * HH + lane]);
            float a5 = b2f(g[(size_t)s5 * HH + lane]);
            float a6 = b2f(g[(size_t)s6 * HH + lane]);
            float a7 = b2f(g[(size_t)s7 * HH + lane]);
            if (ES) {
                acc = fmaf(__shfl(dl, j),     a0, acc);
                acc = fmaf(__shfl(dl, j + 1), a1, acc);
                acc = fmaf(__shfl(dl, j + 2), a2, acc);
                acc = fmaf(__shfl(dl, j + 3), a3, acc);
                acc = fmaf(__shfl(dl, j + 4), a4, acc);
                acc = fmaf(__shfl(dl, j + 5), a5, acc);
                acc = fmaf(__shfl(dl, j + 6), a6, acc);
                acc = fmaf(__shfl(dl, j + 7), a7, acc);
            } else {
                acc += a0; acc += a1; acc += a2; acc += a3;
                acc += a4; acc += a5; acc += a6; acc += a7;
            }
        }
        for (; j < m; ++j) {
            int s = __shfl(sv, j);
            float a = b2f(g[(size_t)s * HH + lane]);
            if (ES) acc = fmaf(__shfl(dl, j), a, acc);
            else acc += a;
        }
    }
    return acc;
}

// ===== fused agg + next GEMM: 8 waves, 8 rows/wave gather; 64x64 GEMM tile =====
template <int ES>
__global__ __launch_bounds__(512, 8) void k_agg_gemm(const int* __restrict__ row_start,
                                                     const int* __restrict__ csr_src,
                                                     const unsigned short* __restrict__ gin,
                                                     const float* __restrict__ dinv,
                                                     const float* __restrict__ bprev,
                                                     const unsigned short* __restrict__ WT,
                                                     unsigned short* __restrict__ gout) {
    __shared__ __align__(16) unsigned short hl[64 * SH];
    int t = threadIdx.x, w = t >> 6, lane = t & 63;
    int row0 = blockIdx.x * 64;
    float b = bprev[lane];
    #pragma unroll 1
    for (int i = 0; i < 8; ++i) {
        int v = row0 + w * 8 + i;
        float outv = 0.f;
        if (v < NN) {
            int st = row_start[v];
            int n = row_start[v + 1] - st;
            float self = b2f(gin[(size_t)v * HH + lane]);
            float acc = ES ? dinv[v] * self : self;
            acc += gather_sum<ES>(csr_src, gin, dinv, st, n, lane);
            outv = relu_f(dinv[v] * acc + b);
        }
        hl[(w * 8 + i) * SH + lane] = f2b(outv);
    }
    __syncthreads();
    int rb = w & 3, cb = w >> 2;
    int m16 = lane & 15, g4 = lane >> 4;
    f32x4 acc2[2] = {{0,0,0,0},{0,0,0,0}};
    const unsigned short* Hrow = &hl[(rb * 16 + m16) * SH + g4 * 8];
    #pragma unroll
    for (int kk = 0; kk < 2; ++kk) {
        short8 a = *reinterpret_cast<const short8*>(Hrow + kk * 32);
        #pragma unroll
        for (int c = 0; c < 2; ++c) {
            int col0 = cb * 32 + c * 16;
            short8 bf = *reinterpret_cast<const short8*>(&WT[(size_t)(col0 + m16) * 64 + g4 * 8 + kk * 32]);
            acc2[c] = __builtin_amdgcn_mfma_f32_16x16x32_bf16(a, bf, acc2[c], 0, 0, 0);
        }
    }
    #pragma unroll
    for (int r = 0; r < 4; ++r) {
        int row = row0 + rb * 16 + g4 * 4 + r;
        if (row < NN) {
            float dv = dinv[row];
            #pragma unroll
            for (int c = 0; c < 2; ++c) {
                int col = cb * 32 + c * 16 + m16;
                gout[(size_t)row * HH + col] = f2b(dv * acc2[c][r]);
            }
        }
    }
}

// ===== final layer: agg + finalize + per-graph partial pool (8 waves, 8 rows) =====
__global__ __launch_bounds__(512, 8) void k_agg_pool(const int* __restrict__ row_start,
                                                     const int* __restrict__ csr_src,
                                                     const unsigned short* __restrict__ gin,
                                                     const float* __restrict__ dinv,
                                                     const float* __restrict__ bL,
                                                     const int* __restrict__ batch,
                                                     int* __restrict__ pgid,
                                                     float* __restrict__ psum,
                                                     float* __restrict__ pooled_fb) {
    int t = threadIdx.x, w = t >> 6, lane = t & 63;
    int row0 = blockIdx.x * 64;
    int widx = blockIdx.x * 8 + w;
    float b = bL[lane];
    int s = 0, cur = -1;
    float ps = 0.f;
    for (int i = 0; i < 8; ++i) {
        int v = row0 + w * 8 + i;
        if (v >= NN) break;
        int st = row_start[v];
        int n = row_start[v + 1] - st;
        float acc = b2f(gin[(size_t)v * HH + lane]);
        acc += gather_sum<0>(csr_src, gin, dinv, st, n, lane);
        float outv = relu_f(dinv[v] * acc + b);
        int gb = batch[v];
        if (gb != cur) {
            if (cur >= 0) {
                if (s < MAXSEG) {
                    if (lane == 0) pgid[widx * MAXSEG + s] = cur;
                    psum[((size_t)widx * MAXSEG + s) * 64 + lane] = ps;
                    s++;
                } else {
                    unsafeAtomicAdd(&pooled_fb[cur * 64 + lane], ps);
                }
            }
            cur = gb; ps = 0.f;
        }
        ps += outv;
    }
    if (cur >= 0) {
        if (s < MAXSEG) {
            if (lane == 0) pgid[widx * MAXSEG + s] = cur;
            psum[((size_t)widx * MAXSEG + s) * 64 + lane] = ps;
            s++;
        } else {
            unsafeAtomicAdd(&pooled_fb[cur * 64 + lane], ps);
        }
    }
    for (; s < MAXSEG; ++s) if (lane == 0) pgid[widx * MAXSEG + s] = -1;
}

// ===== MLP readout: block per graph; reduce partials, then 64->64->32->1 =====
__global__ __launch_bounds__(256) void k_mlp(const int* __restrict__ pgid,
                                             const float* __restrict__ psum,
                                             const float* __restrict__ pooled_fb,
                                             const int* __restrict__ batch,
                                             const float* __restrict__ W1, const float* __restrict__ b1,
                                             const float* __restrict__ W2, const float* __restrict__ b2,
                                             const float* __restrict__ W3, const float* __restrict__ b3,
                                             float* __restrict__ out) {
    int g = blockIdx.x;
    int lo = 0, hi_s = NN;
    while (lo < hi_s) { int mid = (lo + hi_s) >> 1; if (batch[mid] < g) lo = mid + 1; else hi_s = mid; }
    int lo2 = lo, hi = NN;
    while (lo2 < hi) { int mid = (lo2 + hi) >> 1; if (batch[mid] < g + 1) lo2 = mid + 1; else hi = mid; }
    int lane = threadIdx.x & 63, wq = threadIdx.x >> 6;
    float s = 0.f;
    if (hi > lo) {
        int w0 = lo >> 3, w1 = (hi - 1) >> 3;   // 8-row groups
        for (int idx = w0 + wq; idx <= w1; idx += 4) {
            #pragma unroll
            for (int sl = 0; sl < MAXSEG; ++sl) {
                int gid = pgid[idx * MAXSEG + sl];
                if (gid == g) s += psum[((size_t)idx * MAXSEG + sl) * 64 + lane];
            }
        }
    }
    __shared__ float red[4][64];
    __shared__ float pv[64];
    __shared__ float tv[64];
    __shared__ float qv[32];
    red[wq][lane] = s;
    __syncthreads();
    int cnt = hi - lo;
    float invc = 1.f / (float)(cnt > 0 ? cnt : 1);
    if (threadIdx.x < 64) {
        pv[lane] = (red[0][lane] + red[1][lane] + red[2][lane] + red[3][lane]
                    + pooled_fb[g * 64 + lane]) * invc;
    }
    __syncthreads();
    if (threadIdx.x < 64) {
        int j = threadIdx.x;
        float s1 = b1[j];
        #pragma unroll
        for (int k = 0; k < 64; ++k) s1 = fmaf(pv[k], W1[k * 64 + j], s1);
        tv[j] = relu_f(s1);
    }
    __syncthreads();
    if (threadIdx.x < 32) {
        int j = threadIdx.x;
        float s2 = b2[j];
        #pragma unroll
        for (int k = 0; k < 64; ++k) s2 = fmaf(tv[k], W2[k * 32 + j], s2);
        qv[j] = relu_f(s2);
    }
    __syncthreads();
    if (threadIdx.x == 0) {
        float s3 = b3[0];
        #pragma unroll
        for (int k = 0; k < 32; ++k) s3 = fmaf(qv[k], W3[k], s3);
        out[g] = s3;
    }
}

extern "C" void kernel_launch(void* const* d_in, const int* in_sizes, int n_in,
                              void* d_out, int out_size, void* d_ws, size_t ws_size,
                              hipStream_t stream) {
    const float* x    = (const float*)d_in[0];
    const int*   ei   = (const int*)d_in[1];
    const int*   batch= (const int*)d_in[2];
    const float* Wemb = (const float*)d_in[3];
    const float* bemb = (const float*)d_in[4];
    const float* convW= (const float*)d_in[5];
    const float* convb= (const float*)d_in[6];
    const float* W1   = (const float*)d_in[7];
    const float* b1   = (const float*)d_in[8];
    const float* W2   = (const float*)d_in[9];
    const float* b2   = (const float*)d_in[10];
    const float* W3   = (const float*)d_in[11];
    const float* b3   = (const float*)d_in[12];
    float* out = (float*)d_out;

    auto alignup = [](size_t v) { return (v + 255) & ~(size_t)255; };
    char* p = (char*)d_ws;
    int*   row_start    = (int*)p;            p += alignup((size_t)(NN + 1) * 4);
    float* dinv         = (float*)p;          p += alignup((size_t)NN * 4);
    int*   bucket_cnt   = (int*)p;            p += alignup((size_t)NBUCK * 4);
    int*   bucket_start = (int*)p;            p += alignup((size_t)(NBUCK + 1) * 4);
    int*   bucket_cur   = (int*)p;            p += alignup((size_t)NBUCK * 4);
    int*   csr_src      = (int*)p;            p += alignup((size_t)NE * 4);
    unsigned short* WeT = (unsigned short*)p; p += alignup((size_t)64 * 128 * 2);
    unsigned short* WcT = (unsigned short*)p; p += alignup((size_t)3 * 4096 * 2);
    unsigned short* gA  = (unsigned short*)p; p += alignup((size_t)NN * HH * 2);
    unsigned short* gB  = (unsigned short*)p; p += alignup((size_t)NN * HH * 2);
    int*   pgid         = (int*)p;            p += alignup((size_t)NGRP * MAXSEG * 4);
    float* psum         = (float*)p;          p += alignup((size_t)NGRP * MAXSEG * 64 * 4);
    float* pooled_fb    = (float*)p;          p += alignup((size_t)NG * 64 * 4);
    unsigned int* upairs = (unsigned int*)gB; // aliased: gB first written by agg_gemm L0 (csr done by then)

    const int* srcA = ei;
    const int* dstA = ei + NE;

    hipMemsetAsync(bucket_cnt, 0, (size_t)NBUCK * 4, stream);
    hipMemsetAsync(pooled_fb, 0, (size_t)NG * 64 * 4, stream);

    k_prep<<<1, 256, 0, stream>>>(Wemb, convW, WeT, WcT);
    k_bcount<<<NPLACE, 256, 0, stream>>>(dstA, bucket_cnt);
    k_bscan<<<1, 256, 0, stream>>>(bucket_cnt, bucket_start, bucket_cur, row_start);
    k_bplace<<<NPLACE, 256, 0, stream>>>(srcA, dstA, bucket_cur, upairs);

    // CSR finalize overlapped with embed+GEMM0 (embed output unscaled -> no dinv dep)
    k_csr_embed<<<NBUCK + NBLK64, 256, 0, stream>>>(bucket_start, upairs, row_start, dinv,
                                                    csr_src, x, WeT, bemb, WcT /*W0T*/, gA);

    // layer 0 agg (per-edge dinv) + GEMM W1
    k_agg_gemm<1><<<NBLK64, 512, 0, stream>>>(row_start, csr_src, gA, dinv,
                                              convb + 0 * HH, WcT + 1 * 4096, gB);
    // layer 1 agg + GEMM W2
    k_agg_gemm<0><<<NBLK64, 512, 0, stream>>>(row_start, csr_src, gB, dinv,
                                              convb + 1 * HH, WcT + 2 * 4096, gA);
    // layer 2 agg + pool partials
    k_agg_pool<<<NBLK64, 512, 0, stream>>>(row_start, csr_src, gA, dinv,
                                           convb + 2 * HH, batch, pgid, psum, pooled_fb);

    k_mlp<<<NG, 256, 0, stream>>>(pgid, psum, pooled_fb, batch,
                                  W1, b1, W2, b2, W3, b3, out);
}